// Round 1
// 193.362 us; speedup vs baseline: 1.0166x; 1.0166x over previous
//
#include <hip/hip_runtime.h>
#include <stdint.h>

#define NUM_CLASSES 16
#define HW (512 * 512)            // 262144 = 2^18
#define NPIX (8 * HW)             // 2,097,152 pixels
#define NVEC (NPIX / 4)           // 524,288 float4-groups
#define HIST_BINS (NUM_CLASSES * NUM_CLASSES)  // 256

// ext_vector types so __builtin_nontemporal_load accepts them
typedef float floatx4 __attribute__((ext_vector_type(4)));
typedef int   intx4   __attribute__((ext_vector_type(4)));

// Kernel 1: per-pixel argmax over 16 class planes + joint (pred,target)
// histogram. Memory-bound: 16 coalesced float4 streams (one per class plane)
// + 1 int4 target stream. 1 LDS atomic per pixel (joint hist), one global
// atomic flush per block per bin.
//
// 1024 blocks x 256 threads = 4 blocks/CU (VGPR-capped via launch_bounds
// (256,4) -> <=128 VGPR) = 16 waves/CU. Previous 512-block config left
// occupancy at 8 waves/CU, half of what the VGPR budget allows; the serial
// argmax compare chain between load batches then exposed memory latency.
__global__ __launch_bounds__(256, 4) void jaccard_hist_kernel(
    const float* __restrict__ pred,
    const int* __restrict__ target,
    unsigned int* __restrict__ ghist) {
  __shared__ unsigned int lh[HIST_BINS];
  lh[threadIdx.x] = 0u;  // 256 threads cover 256 bins
  __syncthreads();

  int tid = blockIdx.x * blockDim.x + threadIdx.x;
  int stride = gridDim.x * blockDim.x;

  for (int i = tid; i < NVEC; i += stride) {
    int idx4 = i << 2;                 // first pixel of this group
    int b = idx4 >> 18;                // batch index (HW = 2^18)
    int hw = idx4 & (HW - 1);          // offset within plane, multiple of 4
    const float* base = pred + (size_t)b * NUM_CLASSES * HW + hw;

    // Non-temporal: single-use streaming data; the 16 plane streams are
    // 1 MiB apart -> same L2 set index bits, exactly at associativity
    // limit. nt avoids pointless L2 thrash.
    floatx4 best = __builtin_nontemporal_load((const floatx4*)base);
    int ax = 0, ay = 0, az = 0, aw = 0;
#pragma unroll
    for (int c = 1; c < NUM_CLASSES; ++c) {
      floatx4 v = __builtin_nontemporal_load((const floatx4*)(base + (size_t)c * HW));
      // strict > keeps first occurrence of the max (jnp.argmax semantics)
      if (v.x > best.x) { best.x = v.x; ax = c; }
      if (v.y > best.y) { best.y = v.y; ay = c; }
      if (v.z > best.z) { best.z = v.z; az = c; }
      if (v.w > best.w) { best.w = v.w; aw = c; }
    }

    intx4 t = __builtin_nontemporal_load((const intx4*)(target + idx4));
    atomicAdd(&lh[(ax << 4) + t.x], 1u);
    atomicAdd(&lh[(ay << 4) + t.y], 1u);
    atomicAdd(&lh[(az << 4) + t.z], 1u);
    atomicAdd(&lh[(aw << 4) + t.w], 1u);
  }

  __syncthreads();
  // Stagger flush bin by blockIdx so 1024 blocks don't hammer the same
  // ghist address in the same order (same-address atomic RMWs serialize
  // at the owning L2 channel).
  int bin = (threadIdx.x + (blockIdx.x << 4)) & (HIST_BINS - 1);
  unsigned int v = lh[bin];
  if (v) atomicAdd(&ghist[bin], v);
}

// Kernel 2: one wave. counts_p[c] = row sum, counts_t[c] = col sum,
// inter[c] = diagonal; score = inter/union (1.0 if union==0); out = mean.
__global__ __launch_bounds__(64) void jaccard_finalize_kernel(
    const unsigned int* __restrict__ ghist, float* __restrict__ out) {
  __shared__ unsigned int h[HIST_BINS];
  int l = threadIdx.x;  // 0..63
#pragma unroll
  for (int k = 0; k < 4; ++k) h[l + 64 * k] = ghist[l + 64 * k];
  __syncthreads();

  float score = 0.0f;
  if (l < NUM_CLASSES) {
    unsigned int cp = 0, ct = 0;
#pragma unroll
    for (int j = 0; j < NUM_CLASSES; ++j) {
      cp += h[l * 16 + j];   // pred == l
      ct += h[j * 16 + l];   // target == l
    }
    unsigned int inter = h[l * 17];  // pred == target == l
    float uni = (float)cp + (float)ct - (float)inter;
    score = (uni == 0.0f) ? 1.0f : ((float)inter / uni);
  }

  // reduce 16 partial scores living in lanes 0..15 (lanes 16..63 are 0)
#pragma unroll
  for (int off = 8; off >= 1; off >>= 1) score += __shfl_down(score, off, 64);

  if (l == 0) out[0] = score * (1.0f / (float)NUM_CLASSES);
}

extern "C" void kernel_launch(void* const* d_in, const int* in_sizes, int n_in,
                              void* d_out, int out_size, void* d_ws, size_t ws_size,
                              hipStream_t stream) {
  const float* pred = (const float*)d_in[0];
  const int* target = (const int*)d_in[1];
  float* out = (float*)d_out;
  unsigned int* ghist = (unsigned int*)d_ws;

  // d_ws is re-poisoned to 0xAA before every timed call — zero it each time.
  hipMemsetAsync(d_ws, 0, HIST_BINS * sizeof(unsigned int), stream);

  // 1024 blocks x 256 threads, 2 grid-stride iterations/thread, exact coverage.
  jaccard_hist_kernel<<<1024, 256, 0, stream>>>(pred, target, ghist);
  jaccard_finalize_kernel<<<1, 64, 0, stream>>>(ghist, out);
}